// Round 1
// baseline (1390.665 us; speedup 1.0000x reference)
//
#include <hip/hip_runtime.h>
#include <limits.h>

#define NCH 128      // channels C
#define NGR 256      // graphs B
#define NBR 32       // branches K
#define NEG_SLOPE 0.01f

constexpr int CHUNK = 2048;            // nodes per block (phase 1)
constexpr int GWIN  = 2;               // graphs per LDS window
constexpr int SLOTS = GWIN * NBR;      // 64 local slots

__device__ inline float sel4(float4 v, int el) {
    float r = v.x;
    r = (el == 1) ? v.y : r;
    r = (el == 2) ? v.z : r;
    r = (el == 3) ? v.w : r;
    return r;
}

// -------- Phase 1: segment-sum into branch_embed[B*K][C] + per-graph branch max
__global__ __launch_bounds__(256) void scatter_kernel(
    const float* __restrict__ node_embed,   // [N, C]
    const int*   __restrict__ batch,        // [N] sorted
    const int*   __restrict__ branch,       // [N] in [0,K)
    float*       __restrict__ branch_embed, // [B*K, C], pre-zeroed
    int*         __restrict__ max_b,        // [B], pre-init to very negative
    int n_nodes)
{
    __shared__ float acc[SLOTS][NCH];   // 32 KB
    __shared__ int   gmax[GWIN];

    const int t = threadIdx.x;
    for (int i = t; i < SLOTS * NCH; i += 256) ((float*)acc)[i] = 0.0f;
    if (t < GWIN) gmax[t] = INT_MIN;
    __syncthreads();

    const int s = blockIdx.x * CHUNK;
    const int e = min(s + CHUNK, n_nodes);
    const int base = batch[s];          // window base graph (batch sorted)

    // 8 rows per iteration: row r = t>>5, channel-group c4 = t&31 (float4 each)
    const int r  = t >> 5;
    const int c4 = t & 31;
    const int rot = (c4 >> 3) & 3;      // bank-conflict-avoiding rotation

    for (int n0 = s; n0 < e; n0 += 8) {
        const int n = n0 + r;
        if (n < e) {
            const int g  = batch[n];
            const int br = branch[n];
            const float4 v = ((const float4*)node_embed)[(size_t)n * (NCH / 4) + c4];
            const int w = g - base;
            if (w < GWIN) {
                float* dst = &acc[w * NBR + br][0];
                #pragma unroll
                for (int j = 0; j < 4; ++j) {
                    const int el = (j + rot) & 3;           // distinct banks across 32 lanes
                    atomicAdd(&dst[c4 * 4 + el], sel4(v, el));
                }
                if (c4 == 0) atomicMax(&gmax[w], br);
            } else {
                // rare overflow: window exceeded, go straight to global
                float* dst = &branch_embed[((size_t)g * NBR + br) * NCH];
                #pragma unroll
                for (int j = 0; j < 4; ++j)
                    atomicAdd(&dst[c4 * 4 + j], sel4(v, j));
                if (c4 == 0) atomicMax(&max_b[g], br);
            }
        }
    }
    __syncthreads();

    // flush LDS window to global (skip zeros to cut atomic traffic ~2x)
    const size_t gbase = (size_t)base * NBR * NCH;
    const size_t lim   = (size_t)NGR * NBR * NCH;
    for (int i = t; i < SLOTS * NCH; i += 256) {
        const float v = ((float*)acc)[i];
        if (v != 0.0f) {
            const size_t gi = gbase + (size_t)i;
            if (gi < lim) atomicAdd(&branch_embed[gi], v);
        }
    }
    if (t < GWIN) {
        const int g = base + t;
        if (g < NGR && gmax[t] > INT_MIN) atomicMax(&max_b[g], gmax[t]);
    }
}

// -------- Phase 2: per-slot MLP + masked per-graph sum
__global__ __launch_bounds__(256) void mlp_kernel(
    const float* __restrict__ branch_embed, // [B*K, C]
    const int*   __restrict__ max_b,        // [B]
    const float* __restrict__ W1,           // [C, C] row-major
    const float* __restrict__ b1,           // [C]
    const float* __restrict__ W2,           // [C] (C x 1)
    const float* __restrict__ b2,           // [1]
    float*       __restrict__ out)          // [B]
{
    __shared__ float W1s[NCH * NCH];        // 64 KB
    __shared__ float b1s[NCH], W2s[NCH];
    __shared__ float rows[2][NCH];
    __shared__ float red[2][NCH];
    __shared__ float sval[NBR];

    const int t = threadIdx.x;
    const int b = blockIdx.x;

    for (int i = t; i < NCH * NCH / 4; i += 256)
        ((float4*)W1s)[i] = ((const float4*)W1)[i];
    if (t < NCH) { b1s[t] = b1[t]; W2s[t] = W2[t]; }
    __syncthreads();

    const int half = t >> 7;   // which of 2 slots this thread works on
    const int j    = t & 127;  // output channel

    for (int k0 = 0; k0 < NBR; k0 += 2) {
        const int slot = k0 + half;
        rows[half][j] = branch_embed[((size_t)b * NBR + slot) * NCH + j];
        __syncthreads();

        float h = b1s[j];
        #pragma unroll 8
        for (int i = 0; i < NCH; ++i)
            h += rows[half][i] * W1s[i * NCH + j];   // broadcast + 2-way alias (free)
        h = (h >= 0.0f) ? h : NEG_SLOPE * h;
        red[half][j] = h * W2s[j];
        __syncthreads();

        for (int off = 64; off > 0; off >>= 1) {
            if (j < off) red[half][j] += red[half][j + off];
            __syncthreads();
        }
        if (j == 0) sval[slot] = red[half][0];
        __syncthreads();
    }

    if (t < 64) {
        const int mb = max_b[b];
        float v = (t < NBR && t <= mb) ? (sval[t] + b2[0]) : 0.0f;
        #pragma unroll
        for (int off = 32; off > 0; off >>= 1) v += __shfl_down(v, off);
        if (t == 0) out[b] = v;
    }
}

extern "C" void kernel_launch(void* const* d_in, const int* in_sizes, int n_in,
                              void* d_out, int out_size, void* d_ws, size_t ws_size,
                              hipStream_t stream) {
    const float* node_embed = (const float*)d_in[0];
    const int*   batch      = (const int*)d_in[1];
    const int*   branch     = (const int*)d_in[2];
    const float* W1         = (const float*)d_in[3];
    const float* b1         = (const float*)d_in[4];
    const float* W2         = (const float*)d_in[5];
    const float* b2         = (const float*)d_in[6];
    float*       out        = (float*)d_out;

    const int n_nodes = in_sizes[0] / NCH;   // 2,000,000

    float* branch_embed = (float*)d_ws;
    int*   max_b = (int*)((char*)d_ws + (size_t)NGR * NBR * NCH * sizeof(float));

    // accumulators must be re-initialized every call (graph replays)
    hipMemsetAsync(branch_embed, 0, (size_t)NGR * NBR * NCH * sizeof(float), stream);
    hipMemsetAsync(max_b, 0x80, NGR * sizeof(int), stream);  // 0x80808080 << 0 sentinel

    const int grid1 = (n_nodes + CHUNK - 1) / CHUNK;
    scatter_kernel<<<grid1, 256, 0, stream>>>(node_embed, batch, branch,
                                              branch_embed, max_b, n_nodes);
    mlp_kernel<<<NGR, 256, 0, stream>>>(branch_embed, max_b, W1, b1, W2, b2, out);
}